// Round 2
// baseline (233.347 us; speedup 1.0000x reference)
//
#include <hip/hip_runtime.h>
#include <hip/hip_bf16.h>

typedef __attribute__((ext_vector_type(8))) short bf16x8;
typedef __attribute__((ext_vector_type(4))) float f32x4;

#define Bsz 8192
#define Ksz 1024
#define Dsz 64
#define Nsz 4096  // d*d

__device__ __forceinline__ void async_load16(const void* g, void* lds) {
    __builtin_amdgcn_global_load_lds(
        (const __attribute__((address_space(1))) void*)g,
        (__attribute__((address_space(3))) void*)lds,
        16, 0, 0);
}

// ---------------------------------------------------------------------------
// Kernel 1: G [K=1024][N=4096] f32  ->  Gt [N=4096][K=1024] bf16 (transposed)
// ---------------------------------------------------------------------------
__global__ __launch_bounds__(256) void transpose_convert(
    const float* __restrict__ G, __hip_bfloat16* __restrict__ Gt)
{
    __shared__ float tile[64][65];
    const int t = threadIdx.x;
    const int n0 = blockIdx.x * 64;  // N tile
    const int k0 = blockIdx.y * 64;  // K tile

    // read 64x64 f32 tile (coalesced float4)
    for (int i = 0; i < 4; ++i) {
        int f4 = t + 256 * i;            // 1024 float4 chunks
        int row = f4 >> 4;               // k within tile
        int c4  = (f4 & 15) << 2;        // n within tile
        float4 v = *(const float4*)&G[(size_t)(k0 + row) * Nsz + n0 + c4];
        tile[row][c4 + 0] = v.x;
        tile[row][c4 + 1] = v.y;
        tile[row][c4 + 2] = v.z;
        tile[row][c4 + 3] = v.w;
    }
    __syncthreads();
    // write transposed as bf16 (8B stores)
    for (int i = 0; i < 4; ++i) {
        int o = t + 256 * i;
        int rowp = o >> 4;               // n within tile
        int c4   = (o & 15) << 2;        // k within tile
        union { ushort4 u; __hip_bfloat16 h[4]; } cvt;
        cvt.h[0] = __float2bfloat16(tile[c4 + 0][rowp]);
        cvt.h[1] = __float2bfloat16(tile[c4 + 1][rowp]);
        cvt.h[2] = __float2bfloat16(tile[c4 + 2][rowp]);
        cvt.h[3] = __float2bfloat16(tile[c4 + 3][rowp]);
        *(ushort4*)&Gt[(size_t)(n0 + rowp) * Ksz + k0 + c4] = cvt.u;
    }
}

// ---------------------------------------------------------------------------
// Kernel 2: weights  W[b][k] = exp(-bw[k] * max(sqq+sqc-2*dot, 0))  (bf16 out)
// ---------------------------------------------------------------------------
__global__ __launch_bounds__(256) void weights_kernel(
    const float* __restrict__ q, const float* __restrict__ c,
    const float* __restrict__ bw, __hip_bfloat16* __restrict__ W)
{
    __shared__ float qs[128][68];
    __shared__ float cs[128][68];
    __shared__ float sqq[128];
    __shared__ float sqc[128];

    const int t  = threadIdx.x;
    const int b0 = blockIdx.x * 128;
    const int k0 = blockIdx.y * 128;

    // stage q and c tiles (128 rows x 64 f32 each)
    for (int i = 0; i < 8; ++i) {
        int f4 = t + 256 * i;            // 2048 float4 chunks
        int row = f4 >> 4;
        int c4  = (f4 & 15) << 2;
        float4 v = *(const float4*)&q[(size_t)(b0 + row) * Dsz + c4];
        qs[row][c4 + 0] = v.x; qs[row][c4 + 1] = v.y;
        qs[row][c4 + 2] = v.z; qs[row][c4 + 3] = v.w;
        float4 u = *(const float4*)&c[(size_t)(k0 + row) * Dsz + c4];
        cs[row][c4 + 0] = u.x; cs[row][c4 + 1] = u.y;
        cs[row][c4 + 2] = u.z; cs[row][c4 + 3] = u.w;
    }
    __syncthreads();

    if (t < 128) {
        float s = 0.f;
        for (int x = 0; x < 64; ++x) { float v = qs[t][x]; s += v * v; }
        sqq[t] = s;
    } else {
        int r = t - 128;
        float s = 0.f;
        for (int x = 0; x < 64; ++x) { float v = cs[r][x]; s += v * v; }
        sqc[r] = s;
    }
    __syncthreads();

    const int tx = t & 15;   // -> k dimension (coalesced stores)
    const int ty = t >> 4;   // -> b dimension

    float dot[8][8];
    for (int i = 0; i < 8; ++i)
        for (int j = 0; j < 8; ++j) dot[i][j] = 0.f;

    for (int x = 0; x < 64; ++x) {
        float qv[8], cv[8];
        #pragma unroll
        for (int i = 0; i < 8; ++i) qv[i] = qs[ty + 16 * i][x];
        #pragma unroll
        for (int j = 0; j < 8; ++j) cv[j] = cs[tx + 16 * j][x];
        #pragma unroll
        for (int i = 0; i < 8; ++i)
            #pragma unroll
            for (int j = 0; j < 8; ++j)
                dot[i][j] += qv[i] * cv[j];
    }

    for (int j = 0; j < 8; ++j) {
        int k = tx + 16 * j;
        float bwv = bw[k0 + k];
        float sc  = sqc[k];
        for (int i = 0; i < 8; ++i) {
            int b = ty + 16 * i;
            float d2 = fmaxf(sqq[b] + sc - 2.f * dot[i][j], 0.f);
            float w  = __expf(-bwv * d2);
            W[(size_t)(b0 + b) * Ksz + (k0 + k)] = __float2bfloat16(w);
        }
    }
}

// ---------------------------------------------------------------------------
// Kernel 3: C[M=8192][N=4096] = A[M][K] * Bt[N][K]^T  (bf16 in, f32 out)
// m97 structure: 128x128 tile, BK=32, global_load_lds x16, 16x16x32 MFMA.
// Epilogue: +1e-3 on 64x64-block diagonal (n % 65 == 0).
// ---------------------------------------------------------------------------
#define TM 128
#define TN 128
#define BK 32

__global__ __launch_bounds__(256) void gemm_wg(
    const __hip_bfloat16* __restrict__ A,   // W  [M][K]
    const __hip_bfloat16* __restrict__ Bt,  // Gt [N][K]
    float* __restrict__ C)                  // [M][N]
{
    __shared__ __attribute__((aligned(16))) __hip_bfloat16 As[TM * BK];
    __shared__ __attribute__((aligned(16))) __hip_bfloat16 Bs[TN * BK];

    const int t    = threadIdx.x;
    const int wave = t >> 6;
    const int lane = t & 63;
    const int m0 = blockIdx.y * TM;
    const int n0 = blockIdx.x * TN;

    const int wm = (wave >> 1) * 64;   // wave sub-tile offsets
    const int wn = (wave & 1) * 64;
    const int lrow = lane & 15;
    const int lk8  = (lane >> 4) << 3;

    f32x4 acc[4][4];
    for (int i = 0; i < 4; ++i)
        for (int j = 0; j < 4; ++j) acc[i][j] = (f32x4){0.f, 0.f, 0.f, 0.f};

    for (int k0 = 0; k0 < Ksz; k0 += BK) {
        __syncthreads();
        #pragma unroll
        for (int j = 0; j < 2; ++j) {
            int cb    = (wave * 2 + j) * 64;   // chunk base for this wave/call
            int chunk = cb + lane;
            int row   = chunk >> 2;
            int col8  = (chunk & 3) << 3;
            async_load16(A  + (size_t)(m0 + row) * Ksz + k0 + col8, &As[cb * 8]);
            async_load16(Bt + (size_t)(n0 + row) * Ksz + k0 + col8, &Bs[cb * 8]);
        }
        __syncthreads();

        bf16x8 af[4], bfr[4];
        #pragma unroll
        for (int i = 0; i < 4; ++i) {
            af[i]  = *(const bf16x8*)&As[(wm + i * 16 + lrow) * BK + lk8];
            bfr[i] = *(const bf16x8*)&Bs[(wn + i * 16 + lrow) * BK + lk8];
        }
        #pragma unroll
        for (int i = 0; i < 4; ++i)
            #pragma unroll
            for (int j = 0; j < 4; ++j)
                acc[i][j] = __builtin_amdgcn_mfma_f32_16x16x32_bf16(
                    af[i], bfr[j], acc[i][j], 0, 0, 0);
    }

    // epilogue: C/D layout col = lane&15, row = (lane>>4)*4 + reg
    const int crow = (lane >> 4) << 2;
    const int ccol = lane & 15;
    for (int i = 0; i < 4; ++i) {
        for (int j = 0; j < 4; ++j) {
            int gn = n0 + wn + j * 16 + ccol;
            float diag = (gn % 65 == 0) ? 0.001f : 0.f;
            #pragma unroll
            for (int r = 0; r < 4; ++r) {
                int gm = m0 + wm + i * 16 + crow + r;
                C[(size_t)gm * Nsz + gn] = acc[i][j][r] + diag;
            }
        }
    }
}

// ---------------------------------------------------------------------------
extern "C" void kernel_launch(void* const* d_in, const int* in_sizes, int n_in,
                              void* d_out, int out_size, void* d_ws, size_t ws_size,
                              hipStream_t stream) {
    const float* q  = (const float*)d_in[0];
    const float* c  = (const float*)d_in[1];
    const float* bw = (const float*)d_in[2];
    const float* G  = (const float*)d_in[3];
    float* out = (float*)d_out;

    __hip_bfloat16* W  = (__hip_bfloat16*)d_ws;                        // 16 MB
    __hip_bfloat16* Gt = (__hip_bfloat16*)((char*)d_ws + (size_t)16 * 1024 * 1024); // 8 MB

    transpose_convert<<<dim3(Nsz / 64, Ksz / 64), 256, 0, stream>>>(G, Gt);
    weights_kernel<<<dim3(Bsz / 128, Ksz / 128), 256, 0, stream>>>(q, c, bw, W);
    gemm_wg<<<dim3(Nsz / TN, Bsz / TM), 256, 0, stream>>>(W, Gt, out);
}

// Round 3
// 227.470 us; speedup vs baseline: 1.0258x; 1.0258x over previous
//
#include <hip/hip_runtime.h>
#include <hip/hip_bf16.h>

typedef __attribute__((ext_vector_type(8))) short bf16x8;
typedef __attribute__((ext_vector_type(4))) float f32x4;

#define Bsz 8192
#define Ksz 1024
#define Dsz 64
#define Nsz 4096  // d*d

__device__ __forceinline__ void async_load16(const void* g, void* lds) {
    __builtin_amdgcn_global_load_lds(
        (const __attribute__((address_space(1))) void*)g,
        (__attribute__((address_space(3))) void*)lds,
        16, 0, 0);
}

__device__ __forceinline__ float bf2f(unsigned short s) {
    union { unsigned u; float f; } x;
    x.u = ((unsigned)s) << 16;
    return x.f;
}

// ---------------------------------------------------------------------------
// Kernel 1: G [K=1024][N=4096] f32  ->  Gt [N=4096][K=1024] bf16 (transposed)
// ---------------------------------------------------------------------------
__global__ __launch_bounds__(256) void transpose_convert(
    const float* __restrict__ G, __hip_bfloat16* __restrict__ Gt)
{
    __shared__ float tile[64][65];
    const int t = threadIdx.x;
    const int n0 = blockIdx.x * 64;  // N tile
    const int k0 = blockIdx.y * 64;  // K tile

    for (int i = 0; i < 4; ++i) {
        int f4 = t + 256 * i;
        int row = f4 >> 4;
        int c4  = (f4 & 15) << 2;
        float4 v = *(const float4*)&G[(size_t)(k0 + row) * Nsz + n0 + c4];
        tile[row][c4 + 0] = v.x;
        tile[row][c4 + 1] = v.y;
        tile[row][c4 + 2] = v.z;
        tile[row][c4 + 3] = v.w;
    }
    __syncthreads();
    for (int i = 0; i < 4; ++i) {
        int o = t + 256 * i;
        int rowp = o >> 4;
        int c4   = (o & 15) << 2;
        union { ushort4 u; __hip_bfloat16 h[4]; } cvt;
        cvt.h[0] = __float2bfloat16(tile[c4 + 0][rowp]);
        cvt.h[1] = __float2bfloat16(tile[c4 + 1][rowp]);
        cvt.h[2] = __float2bfloat16(tile[c4 + 2][rowp]);
        cvt.h[3] = __float2bfloat16(tile[c4 + 3][rowp]);
        *(ushort4*)&Gt[(size_t)(n0 + rowp) * Ksz + k0 + c4] = cvt.u;
    }
}

// ---------------------------------------------------------------------------
// Kernel 2: weights via MFMA with split-bf16 (hi+lo) precision.
// W[b][k] = exp(-bw[k] * max(sqq[b]+sqc[k]-2*q.c, 0)), bf16 out.
// c is pre-scaled by 2 so the MFMA directly accumulates 2*q.c.
// dot = qh*ch + qh*cl + ql*ch  (ql*cl dropped, ~1e-4 abs — negligible)
// ---------------------------------------------------------------------------
#define QSTR 72  // padded LDS row stride (bf16): 144 B rows, 16-B aligned, 2-way banks

__global__ __launch_bounds__(256) void weights_mfma(
    const float* __restrict__ q, const float* __restrict__ c,
    const float* __restrict__ bw, __hip_bfloat16* __restrict__ W)
{
    __shared__ __attribute__((aligned(16))) __hip_bfloat16 qh[128 * QSTR];
    __shared__ __attribute__((aligned(16))) __hip_bfloat16 ql[128 * QSTR];
    __shared__ __attribute__((aligned(16))) __hip_bfloat16 ch[128 * QSTR];
    __shared__ __attribute__((aligned(16))) __hip_bfloat16 cl[128 * QSTR];
    __shared__ float sqq[128];
    __shared__ float sqc[128];

    const int t  = threadIdx.x;
    const int b0 = blockIdx.x * 128;
    const int k0 = blockIdx.y * 128;

    // stage + split: 128 rows x 64 f32 of q and of 2*c
    for (int i = 0; i < 8; ++i) {
        int f4  = t + 256 * i;           // 2048 float4 chunks
        int row = f4 >> 4;
        int c4  = (f4 & 15) << 2;
        float4 v = *(const float4*)&q[(size_t)(b0 + row) * Dsz + c4];
        float4 u = *(const float4*)&c[(size_t)(k0 + row) * Dsz + c4];
        float qv[4] = {v.x, v.y, v.z, v.w};
        float cv[4] = {2.f * u.x, 2.f * u.y, 2.f * u.z, 2.f * u.w};
        union { ushort4 u4; __hip_bfloat16 h[4]; } qhh, qll, chh, cll;
        #pragma unroll
        for (int e = 0; e < 4; ++e) {
            __hip_bfloat16 hb = __float2bfloat16(qv[e]);
            qhh.h[e] = hb;
            qll.h[e] = __float2bfloat16(qv[e] - bf2f(*(unsigned short*)&hb));
            __hip_bfloat16 hc = __float2bfloat16(cv[e]);
            chh.h[e] = hc;
            cll.h[e] = __float2bfloat16(cv[e] - bf2f(*(unsigned short*)&hc));
        }
        *(ushort4*)&qh[row * QSTR + c4] = qhh.u4;
        *(ushort4*)&ql[row * QSTR + c4] = qll.u4;
        *(ushort4*)&ch[row * QSTR + c4] = chh.u4;
        *(ushort4*)&cl[row * QSTR + c4] = cll.u4;
    }
    __syncthreads();

    // row sums of the RECONSTRUCTED values (consistent with the MFMA dot)
    if (t < 128) {
        float s = 0.f;
        for (int x8 = 0; x8 < 64; x8 += 8) {
            bf16x8 h = *(const bf16x8*)&qh[t * QSTR + x8];
            bf16x8 l = *(const bf16x8*)&ql[t * QSTR + x8];
            #pragma unroll
            for (int e = 0; e < 8; ++e) {
                float v = bf2f((unsigned short)h[e]) + bf2f((unsigned short)l[e]);
                s += v * v;
            }
        }
        sqq[t] = s;
    } else {
        int r = t - 128;
        float s = 0.f;
        for (int x8 = 0; x8 < 64; x8 += 8) {
            bf16x8 h = *(const bf16x8*)&ch[r * QSTR + x8];
            bf16x8 l = *(const bf16x8*)&cl[r * QSTR + x8];
            #pragma unroll
            for (int e = 0; e < 8; ++e) {
                float v = 0.5f * (bf2f((unsigned short)h[e]) + bf2f((unsigned short)l[e]));
                s += v * v;
            }
        }
        sqc[r] = s;
    }
    __syncthreads();

    const int wave = t >> 6;
    const int lane = t & 63;
    const int wm = (wave >> 1) * 64;
    const int wn = (wave & 1) * 64;
    const int lrow = lane & 15;
    const int lk8  = (lane >> 4) << 3;

    f32x4 acc[4][4];
    for (int i = 0; i < 4; ++i)
        for (int j = 0; j < 4; ++j) acc[i][j] = (f32x4){0.f, 0.f, 0.f, 0.f};

    #pragma unroll
    for (int ks = 0; ks < 64; ks += 32) {
        bf16x8 ah[4], al[4], bh[4], bl[4];
        #pragma unroll
        for (int i = 0; i < 4; ++i) {
            int ra = (wm + i * 16 + lrow) * QSTR + ks + lk8;
            int rb = (wn + i * 16 + lrow) * QSTR + ks + lk8;
            ah[i] = *(const bf16x8*)&qh[ra];
            al[i] = *(const bf16x8*)&ql[ra];
            bh[i] = *(const bf16x8*)&ch[rb];
            bl[i] = *(const bf16x8*)&cl[rb];
        }
        #pragma unroll
        for (int i = 0; i < 4; ++i)
            #pragma unroll
            for (int j = 0; j < 4; ++j) {
                acc[i][j] = __builtin_amdgcn_mfma_f32_16x16x32_bf16(ah[i], bh[j], acc[i][j], 0, 0, 0);
                acc[i][j] = __builtin_amdgcn_mfma_f32_16x16x32_bf16(ah[i], bl[j], acc[i][j], 0, 0, 0);
                acc[i][j] = __builtin_amdgcn_mfma_f32_16x16x32_bf16(al[i], bh[j], acc[i][j], 0, 0, 0);
            }
    }

    // epilogue: acc = 2*q.c ; C/D layout col=lane&15 (k), row=(lane>>4)*4+r (b)
    const int crow = (lane >> 4) << 2;
    const int ccol = lane & 15;
    for (int j = 0; j < 4; ++j) {
        int k = wn + j * 16 + ccol;
        float bwv = bw[k0 + k];
        float sc  = sqc[k];
        #pragma unroll
        for (int i = 0; i < 4; ++i) {
            #pragma unroll
            for (int r = 0; r < 4; ++r) {
                int b = wm + i * 16 + crow + r;
                float d2 = fmaxf(sqq[b] + sc - acc[i][j][r], 0.f);
                W[(size_t)(b0 + b) * Ksz + (k0 + k)] = __float2bfloat16(__expf(-bwv * d2));
            }
        }
    }
}

// ---------------------------------------------------------------------------
// Kernel 3: C[M=8192][N=4096] = A[M][K] * Bt[N][K]^T  (bf16 in, f32 out)
// ---------------------------------------------------------------------------
#define TM 128
#define TN 128
#define BK 32

__global__ __launch_bounds__(256) void gemm_wg(
    const __hip_bfloat16* __restrict__ A,   // W  [M][K]
    const __hip_bfloat16* __restrict__ Bt,  // Gt [N][K]
    float* __restrict__ C)                  // [M][N]
{
    __shared__ __attribute__((aligned(16))) __hip_bfloat16 As[TM * BK];
    __shared__ __attribute__((aligned(16))) __hip_bfloat16 Bs[TN * BK];

    const int t    = threadIdx.x;
    const int wave = t >> 6;
    const int lane = t & 63;
    const int m0 = blockIdx.y * TM;
    const int n0 = blockIdx.x * TN;

    const int wm = (wave >> 1) * 64;
    const int wn = (wave & 1) * 64;
    const int lrow = lane & 15;
    const int lk8  = (lane >> 4) << 3;

    f32x4 acc[4][4];
    for (int i = 0; i < 4; ++i)
        for (int j = 0; j < 4; ++j) acc[i][j] = (f32x4){0.f, 0.f, 0.f, 0.f};

    for (int k0 = 0; k0 < Ksz; k0 += BK) {
        __syncthreads();
        #pragma unroll
        for (int j = 0; j < 2; ++j) {
            int cb    = (wave * 2 + j) * 64;
            int chunk = cb + lane;
            int row   = chunk >> 2;
            int col8  = (chunk & 3) << 3;
            async_load16(A  + (size_t)(m0 + row) * Ksz + k0 + col8, &As[cb * 8]);
            async_load16(Bt + (size_t)(n0 + row) * Ksz + k0 + col8, &Bs[cb * 8]);
        }
        __syncthreads();

        bf16x8 af[4], bfr[4];
        #pragma unroll
        for (int i = 0; i < 4; ++i) {
            af[i]  = *(const bf16x8*)&As[(wm + i * 16 + lrow) * BK + lk8];
            bfr[i] = *(const bf16x8*)&Bs[(wn + i * 16 + lrow) * BK + lk8];
        }
        #pragma unroll
        for (int i = 0; i < 4; ++i)
            #pragma unroll
            for (int j = 0; j < 4; ++j)
                acc[i][j] = __builtin_amdgcn_mfma_f32_16x16x32_bf16(
                    af[i], bfr[j], acc[i][j], 0, 0, 0);
    }

    const int crow = (lane >> 4) << 2;
    const int ccol = lane & 15;
    for (int i = 0; i < 4; ++i) {
        for (int j = 0; j < 4; ++j) {
            int gn = n0 + wn + j * 16 + ccol;
            float diag = (gn % 65 == 0) ? 0.001f : 0.f;
            #pragma unroll
            for (int r = 0; r < 4; ++r) {
                int gm = m0 + wm + i * 16 + crow + r;
                C[(size_t)gm * Nsz + gn] = acc[i][j][r] + diag;
            }
        }
    }
}

// ---------------------------------------------------------------------------
extern "C" void kernel_launch(void* const* d_in, const int* in_sizes, int n_in,
                              void* d_out, int out_size, void* d_ws, size_t ws_size,
                              hipStream_t stream) {
    const float* q  = (const float*)d_in[0];
    const float* c  = (const float*)d_in[1];
    const float* bw = (const float*)d_in[2];
    const float* G  = (const float*)d_in[3];
    float* out = (float*)d_out;

    __hip_bfloat16* W  = (__hip_bfloat16*)d_ws;                        // 16 MB
    __hip_bfloat16* Gt = (__hip_bfloat16*)((char*)d_ws + (size_t)16 * 1024 * 1024); // 8 MB

    transpose_convert<<<dim3(Nsz / 64, Ksz / 64), 256, 0, stream>>>(G, Gt);
    weights_mfma<<<dim3(Bsz / 128, Ksz / 128), 256, 0, stream>>>(q, c, bw, W);
    gemm_wg<<<dim3(Nsz / TN, Bsz / TM), 256, 0, stream>>>(W, Gt, out);
}

// Round 4
// 226.691 us; speedup vs baseline: 1.0294x; 1.0034x over previous
//
#include <hip/hip_runtime.h>
#include <hip/hip_bf16.h>

typedef __attribute__((ext_vector_type(8))) short bf16x8;
typedef __attribute__((ext_vector_type(4))) float f32x4;

#define Bsz 8192
#define Ksz 1024
#define Dsz 64
#define Nsz 4096  // d*d

__device__ __forceinline__ void async_load16(const void* g, void* lds) {
    __builtin_amdgcn_global_load_lds(
        (const __attribute__((address_space(1))) void*)g,
        (__attribute__((address_space(3))) void*)lds,
        16, 0, 0);
}

__device__ __forceinline__ float bf2f(unsigned short s) {
    union { unsigned u; float f; } x;
    x.u = ((unsigned)s) << 16;
    return x.f;
}

// ---------------------------------------------------------------------------
// Kernel 1: G [K=1024][N=4096] f32  ->  Gt [N=4096][K=1024] bf16 (transposed)
// ---------------------------------------------------------------------------
__global__ __launch_bounds__(256) void transpose_convert(
    const float* __restrict__ G, __hip_bfloat16* __restrict__ Gt)
{
    __shared__ float tile[64][65];
    const int t = threadIdx.x;
    const int n0 = blockIdx.x * 64;  // N tile
    const int k0 = blockIdx.y * 64;  // K tile

    for (int i = 0; i < 4; ++i) {
        int f4 = t + 256 * i;
        int row = f4 >> 4;
        int c4  = (f4 & 15) << 2;
        float4 v = *(const float4*)&G[(size_t)(k0 + row) * Nsz + n0 + c4];
        tile[row][c4 + 0] = v.x;
        tile[row][c4 + 1] = v.y;
        tile[row][c4 + 2] = v.z;
        tile[row][c4 + 3] = v.w;
    }
    __syncthreads();
    for (int i = 0; i < 4; ++i) {
        int o = t + 256 * i;
        int rowp = o >> 4;
        int c4   = (o & 15) << 2;
        union { ushort4 u; __hip_bfloat16 h[4]; } cvt;
        cvt.h[0] = __float2bfloat16(tile[c4 + 0][rowp]);
        cvt.h[1] = __float2bfloat16(tile[c4 + 1][rowp]);
        cvt.h[2] = __float2bfloat16(tile[c4 + 2][rowp]);
        cvt.h[3] = __float2bfloat16(tile[c4 + 3][rowp]);
        *(ushort4*)&Gt[(size_t)(n0 + rowp) * Ksz + k0 + c4] = cvt.u;
    }
}

// ---------------------------------------------------------------------------
// Kernel 2: weights via MFMA with split-bf16 (hi+lo) precision.
// ---------------------------------------------------------------------------
#define QSTR 72

__global__ __launch_bounds__(256) void weights_mfma(
    const float* __restrict__ q, const float* __restrict__ c,
    const float* __restrict__ bw, __hip_bfloat16* __restrict__ W)
{
    __shared__ __attribute__((aligned(16))) __hip_bfloat16 qh[128 * QSTR];
    __shared__ __attribute__((aligned(16))) __hip_bfloat16 ql[128 * QSTR];
    __shared__ __attribute__((aligned(16))) __hip_bfloat16 ch[128 * QSTR];
    __shared__ __attribute__((aligned(16))) __hip_bfloat16 cl[128 * QSTR];
    __shared__ float sqq[128];
    __shared__ float sqc[128];

    const int t  = threadIdx.x;
    const int b0 = blockIdx.x * 128;
    const int k0 = blockIdx.y * 128;

    for (int i = 0; i < 8; ++i) {
        int f4  = t + 256 * i;
        int row = f4 >> 4;
        int c4  = (f4 & 15) << 2;
        float4 v = *(const float4*)&q[(size_t)(b0 + row) * Dsz + c4];
        float4 u = *(const float4*)&c[(size_t)(k0 + row) * Dsz + c4];
        float qv[4] = {v.x, v.y, v.z, v.w};
        float cv[4] = {2.f * u.x, 2.f * u.y, 2.f * u.z, 2.f * u.w};
        union { ushort4 u4; __hip_bfloat16 h[4]; } qhh, qll, chh, cll;
        #pragma unroll
        for (int e = 0; e < 4; ++e) {
            __hip_bfloat16 hb = __float2bfloat16(qv[e]);
            qhh.h[e] = hb;
            qll.h[e] = __float2bfloat16(qv[e] - bf2f(*(unsigned short*)&hb));
            __hip_bfloat16 hc = __float2bfloat16(cv[e]);
            chh.h[e] = hc;
            cll.h[e] = __float2bfloat16(cv[e] - bf2f(*(unsigned short*)&hc));
        }
        *(ushort4*)&qh[row * QSTR + c4] = qhh.u4;
        *(ushort4*)&ql[row * QSTR + c4] = qll.u4;
        *(ushort4*)&ch[row * QSTR + c4] = chh.u4;
        *(ushort4*)&cl[row * QSTR + c4] = cll.u4;
    }
    __syncthreads();

    if (t < 128) {
        float s = 0.f;
        for (int x8 = 0; x8 < 64; x8 += 8) {
            bf16x8 h = *(const bf16x8*)&qh[t * QSTR + x8];
            bf16x8 l = *(const bf16x8*)&ql[t * QSTR + x8];
            #pragma unroll
            for (int e = 0; e < 8; ++e) {
                float v = bf2f((unsigned short)h[e]) + bf2f((unsigned short)l[e]);
                s += v * v;
            }
        }
        sqq[t] = s;
    } else {
        int r = t - 128;
        float s = 0.f;
        for (int x8 = 0; x8 < 64; x8 += 8) {
            bf16x8 h = *(const bf16x8*)&ch[r * QSTR + x8];
            bf16x8 l = *(const bf16x8*)&cl[r * QSTR + x8];
            #pragma unroll
            for (int e = 0; e < 8; ++e) {
                float v = 0.5f * (bf2f((unsigned short)h[e]) + bf2f((unsigned short)l[e]));
                s += v * v;
            }
        }
        sqc[r] = s;
    }
    __syncthreads();

    const int wave = t >> 6;
    const int lane = t & 63;
    const int wm = (wave >> 1) * 64;
    const int wn = (wave & 1) * 64;
    const int lrow = lane & 15;
    const int lk8  = (lane >> 4) << 3;

    f32x4 acc[4][4];
    for (int i = 0; i < 4; ++i)
        for (int j = 0; j < 4; ++j) acc[i][j] = (f32x4){0.f, 0.f, 0.f, 0.f};

    #pragma unroll
    for (int ks = 0; ks < 64; ks += 32) {
        bf16x8 ah[4], al[4], bh[4], bl[4];
        #pragma unroll
        for (int i = 0; i < 4; ++i) {
            int ra = (wm + i * 16 + lrow) * QSTR + ks + lk8;
            int rb = (wn + i * 16 + lrow) * QSTR + ks + lk8;
            ah[i] = *(const bf16x8*)&qh[ra];
            al[i] = *(const bf16x8*)&ql[ra];
            bh[i] = *(const bf16x8*)&ch[rb];
            bl[i] = *(const bf16x8*)&cl[rb];
        }
        #pragma unroll
        for (int i = 0; i < 4; ++i)
            #pragma unroll
            for (int j = 0; j < 4; ++j) {
                acc[i][j] = __builtin_amdgcn_mfma_f32_16x16x32_bf16(ah[i], bh[j], acc[i][j], 0, 0, 0);
                acc[i][j] = __builtin_amdgcn_mfma_f32_16x16x32_bf16(ah[i], bl[j], acc[i][j], 0, 0, 0);
                acc[i][j] = __builtin_amdgcn_mfma_f32_16x16x32_bf16(al[i], bh[j], acc[i][j], 0, 0, 0);
            }
    }

    const int crow = (lane >> 4) << 2;
    const int ccol = lane & 15;
    for (int j = 0; j < 4; ++j) {
        int k = wn + j * 16 + ccol;
        float bwv = bw[k0 + k];
        float sc  = sqc[k];
        #pragma unroll
        for (int i = 0; i < 4; ++i) {
            #pragma unroll
            for (int r = 0; r < 4; ++r) {
                int b = wm + i * 16 + crow + r;
                float d2 = fmaxf(sqq[b] + sc - acc[i][j][r], 0.f);
                W[(size_t)(b0 + b) * Ksz + (k0 + k)] = __float2bfloat16(__expf(-bwv * d2));
            }
        }
    }
}

// ---------------------------------------------------------------------------
// Kernel 3: C[M][N] = A[M][K] * Bt[N][K]^T  (bf16 in, f32 out)
// BK=64 (32 MFMA per barrier) + XOR bank swizzle (col8 ^= row&7) applied on
// the global-side chunk assignment (global_load_lds slots are lane-fixed)
// and mirrored in the fragment reads.
// ---------------------------------------------------------------------------
#define TM 128
#define TN 128
#define BK 64

__global__ __launch_bounds__(256) void gemm_wg(
    const __hip_bfloat16* __restrict__ A,   // W  [M][K]
    const __hip_bfloat16* __restrict__ Bt,  // Gt [N][K]
    float* __restrict__ C)                  // [M][N]
{
    __shared__ __attribute__((aligned(16))) __hip_bfloat16 As[TM * BK]; // 16 KB
    __shared__ __attribute__((aligned(16))) __hip_bfloat16 Bs[TN * BK]; // 16 KB

    const int t    = threadIdx.x;
    const int wave = t >> 6;
    const int lane = t & 63;
    const int m0 = blockIdx.y * TM;
    const int n0 = blockIdx.x * TN;

    const int wm = (wave >> 1) * 64;
    const int wn = (wave & 1) * 64;
    const int lrow = lane & 15;
    const int kg   = lane >> 4;           // 0..3 (k-group within MFMA frag)

    f32x4 acc[4][4];
    for (int i = 0; i < 4; ++i)
        for (int j = 0; j < 4; ++j) acc[i][j] = (f32x4){0.f, 0.f, 0.f, 0.f};

    for (int k0 = 0; k0 < Ksz; k0 += BK) {
        __syncthreads();
        // stage A and B tiles: 128 rows x 64 bf16 each = 1024 16B-chunks/matrix
        #pragma unroll
        for (int r = 0; r < 4; ++r) {
            int chunk = r * 256 + wave * 64 + lane;
            int row   = chunk >> 3;           // 0..127
            int c8    = chunk & 7;            // LDS col-block (8 bf16 each)
            int g8    = c8 ^ (row & 7);       // swizzled global col-block
            async_load16(A  + (size_t)(m0 + row) * Ksz + k0 + g8 * 8, &As[chunk * 8]);
            async_load16(Bt + (size_t)(n0 + row) * Ksz + k0 + g8 * 8, &Bs[chunk * 8]);
        }
        __syncthreads();

        #pragma unroll
        for (int ks = 0; ks < 2; ++ks) {
            bf16x8 af[4], bfr[4];
            #pragma unroll
            for (int i = 0; i < 4; ++i) {
                int ra = wm + i * 16 + lrow;
                int ca = ((ks * 4 + kg) ^ (ra & 7)) * 8;
                af[i] = *(const bf16x8*)&As[ra * BK + ca];
                int rb = wn + i * 16 + lrow;
                int cb = ((ks * 4 + kg) ^ (rb & 7)) * 8;
                bfr[i] = *(const bf16x8*)&Bs[rb * BK + cb];
            }
            #pragma unroll
            for (int i = 0; i < 4; ++i)
                #pragma unroll
                for (int j = 0; j < 4; ++j)
                    acc[i][j] = __builtin_amdgcn_mfma_f32_16x16x32_bf16(
                        af[i], bfr[j], acc[i][j], 0, 0, 0);
        }
    }

    // epilogue: C/D layout col = lane&15, row = (lane>>4)*4 + reg
    const int crow = (lane >> 4) << 2;
    const int ccol = lane & 15;
    for (int i = 0; i < 4; ++i) {
        for (int j = 0; j < 4; ++j) {
            int gn = n0 + wn + j * 16 + ccol;
            float diag = (gn % 65 == 0) ? 0.001f : 0.f;
            #pragma unroll
            for (int r = 0; r < 4; ++r) {
                int gm = m0 + wm + i * 16 + crow + r;
                C[(size_t)gm * Nsz + gn] = acc[i][j][r] + diag;
            }
        }
    }
}

// ---------------------------------------------------------------------------
extern "C" void kernel_launch(void* const* d_in, const int* in_sizes, int n_in,
                              void* d_out, int out_size, void* d_ws, size_t ws_size,
                              hipStream_t stream) {
    const float* q  = (const float*)d_in[0];
    const float* c  = (const float*)d_in[1];
    const float* bw = (const float*)d_in[2];
    const float* G  = (const float*)d_in[3];
    float* out = (float*)d_out;

    __hip_bfloat16* W  = (__hip_bfloat16*)d_ws;                        // 16 MB
    __hip_bfloat16* Gt = (__hip_bfloat16*)((char*)d_ws + (size_t)16 * 1024 * 1024); // 8 MB

    transpose_convert<<<dim3(Nsz / 64, Ksz / 64), 256, 0, stream>>>(G, Gt);
    weights_mfma<<<dim3(Bsz / 128, Ksz / 128), 256, 0, stream>>>(q, c, bw, W);
    gemm_wg<<<dim3(Nsz / TN, Bsz / TM), 256, 0, stream>>>(W, Gt, out);
}